// Round 2
// baseline (194.438 us; speedup 1.0000x reference)
//
#include <hip/hip_runtime.h>
#include <hip/hip_bf16.h>
#include <cmath>

#define B_N 8192
#define D_K 128
#define CSPLIT 2           // column splits per 32-row group
#define T_ITERS 16         // 32-col tiles per wave: 4096 cols / 8 waves / 32

typedef short bf16x8 __attribute__((ext_vector_type(8)));
typedef float f32x16 __attribute__((ext_vector_type(16)));

__device__ inline unsigned short f2bf(float f) {
    unsigned u = __builtin_bit_cast(unsigned, f);
    u += 0x7fffu + ((u >> 16) & 1u);   // round-to-nearest-even
    return (unsigned short)(u >> 16);
}

// Convert fp32 Q and A to bf16 in workspace. One thread per 4 elements.
__global__ void cvt_kernel(const float* __restrict__ q, const float* __restrict__ a,
                           unsigned short* __restrict__ qb, unsigned short* __restrict__ ab) {
    int i = blockIdx.x * blockDim.x + threadIdx.x;   // 0 .. B*D/4-1
    float4 vq = reinterpret_cast<const float4*>(q)[i];
    float4 va = reinterpret_cast<const float4*>(a)[i];
    ushort4 oq, oa;
    oq.x = f2bf(vq.x); oq.y = f2bf(vq.y); oq.z = f2bf(vq.z); oq.w = f2bf(vq.w);
    oa.x = f2bf(va.x); oa.y = f2bf(va.y); oa.z = f2bf(va.z); oa.w = f2bf(va.w);
    reinterpret_cast<ushort4*>(qb)[i] = oq;
    reinterpret_cast<ushort4*>(ab)[i] = oa;
}

// Partial kernel: block (rg, cs) computes rows [rg*32, rg*32+32) over cols
// [cs*4096, cs*4096+4096). 512 threads = 8 waves; wave w owns 512 cols.
// MFMA 32x32x16 bf16. C/D layout: col = lane&31, row = (reg&3) + 8*(reg>>2) + 4*(lane>>5).
// __launch_bounds__(512,4): 4 waves/EU -> 2 blocks/CU (16 waves/CU), VGPR cap 128.
__launch_bounds__(512, 4)
__global__ void mpl_part_kernel(const unsigned short* __restrict__ qb,
                                const unsigned short* __restrict__ ab,
                                const int* __restrict__ qids,
                                const float* __restrict__ ranks,
                                float* __restrict__ pden, float* __restrict__ pnum,
                                float* __restrict__ pmax, int* __restrict__ pidx) {
    const int tid  = threadIdx.x;
    const int lane = tid & 63;
    const int wave = tid >> 6;               // 0..7
    const int rg   = blockIdx.x >> 1;        // 0..255
    const int cs   = blockIdx.x & 1;         // 0..1
    const int rowBase = rg * 32;
    const int half = lane >> 5;              // 0 or 1
    const int l31  = lane & 31;

    // Q fragments for the whole K=128 (8 MFMA k-steps), kept in registers.
    bf16x8 qfrag[8];
    {
        const unsigned short* qrow = qb + (size_t)(rowBase + l31) * D_K + half * 8;
        #pragma unroll
        for (int s = 0; s < 8; ++s)
            qfrag[s] = *reinterpret_cast<const bf16x8*>(qrow + s * 16);
    }

    int qidrow[16];
    #pragma unroll
    for (int r = 0; r < 16; ++r)
        qidrow[r] = qids[rowBase + (r & 3) + 8 * (r >> 2) + 4 * half];

    float den[16], num[16], mxv[16];
    int mxi[16];
    #pragma unroll
    for (int r = 0; r < 16; ++r) { den[r] = 0.f; num[r] = 0.f; mxv[r] = -INFINITY; mxi[r] = 0x7fffffff; }

    const float L2E = 1.4426950408889634f;   // log2(e)
    const float CB  = 64.0f;                 // fixed exponent bias; cancels in num/den

    const int colStart = cs * 4096 + wave * 512;

    // 2-deep pipeline: loads for tile t+1 issue before the MFMA/epilogue of tile t.
    const unsigned short* aptr = ab + (size_t)(colStart + l31) * D_K + half * 8;
    bf16x8 bcur[8], bnxt[8];
    #pragma unroll
    for (int s = 0; s < 8; ++s) bcur[s] = *reinterpret_cast<const bf16x8*>(aptr + s * 16);
    int   qc_c = qids[colStart + l31];
    float wc_c = 1.0f - 0.1f * ranks[colStart + l31];

    for (int t = 0; t < T_ITERS; ++t) {
        const int c = colStart + t * 32 + l31;
        // prefetch t+1 (last iter re-reads t=0's tile: valid addr, result unused)
        const int tn = (t + 1 < T_ITERS) ? (t + 1) : 0;
        const unsigned short* anext = ab + (size_t)(colStart + tn * 32 + l31) * D_K + half * 8;
        #pragma unroll
        for (int s = 0; s < 8; ++s) bnxt[s] = *reinterpret_cast<const bf16x8*>(anext + s * 16);
        const int   qn = qids[colStart + tn * 32 + l31];
        const float wn = 1.0f - 0.1f * ranks[colStart + tn * 32 + l31];

        f32x16 acc;
        #pragma unroll
        for (int i = 0; i < 16; ++i) acc[i] = 0.f;
        #pragma unroll
        for (int s = 0; s < 8; ++s)
            acc = __builtin_amdgcn_mfma_f32_32x32x16_bf16(qfrag[s], bcur[s], acc, 0, 0, 0);

        #pragma unroll
        for (int r = 0; r < 16; ++r) {
            float sv = acc[r];
            float e  = exp2f(fmaf(sv, L2E, -CB));   // e^sv * 2^-CB
            den[r] += e;
            float ws = (qc_c == qidrow[r]) ? wc_c : 0.0f;
            num[r] = fmaf(ws, e, num[r]);
            bool gt = sv > mxv[r];                  // strict > keeps first occurrence
            mxv[r] = gt ? sv : mxv[r];
            mxi[r] = gt ? c  : mxi[r];
        }

        #pragma unroll
        for (int s = 0; s < 8; ++s) bcur[s] = bnxt[s];
        qc_c = qn; wc_c = wn;
    }

    // Cross-lane merge within each 32-lane half (each half owns the same 16 rows).
    #pragma unroll
    for (int m = 1; m <= 16; m <<= 1) {
        #pragma unroll
        for (int r = 0; r < 16; ++r) {
            float od = __shfl_xor(den[r], m, 64);
            float on = __shfl_xor(num[r], m, 64);
            float ov = __shfl_xor(mxv[r], m, 64);
            int   oi = __shfl_xor(mxi[r], m, 64);
            den[r] += od;
            num[r] += on;
            if (ov > mxv[r] || (ov == mxv[r] && oi < mxi[r])) { mxv[r] = ov; mxi[r] = oi; }
        }
    }

    __shared__ float sden[8][32], snum[8][32], smax[8][32];
    __shared__ int   sidx[8][32];
    if (l31 == 0) {
        #pragma unroll
        for (int r = 0; r < 16; ++r) {
            int lr = (r & 3) + 8 * (r >> 2) + 4 * half;
            sden[wave][lr] = den[r];
            snum[wave][lr] = num[r];
            smax[wave][lr] = mxv[r];
            sidx[wave][lr] = mxi[r];
        }
    }
    __syncthreads();

    if (tid < 32) {
        int lr = tid;
        float d = 0.f, n = 0.f, mv = -INFINITY;
        int mi = 0x7fffffff;
        #pragma unroll
        for (int w = 0; w < 8; ++w) {
            d += sden[w][lr];
            n += snum[w][lr];
            float ov = smax[w][lr]; int oi = sidx[w][lr];
            if (ov > mv || (ov == mv && oi < mi)) { mv = ov; mi = oi; }
        }
        const int row = rowBase + lr;
        pden[cs * B_N + row] = d;
        pnum[cs * B_N + row] = n;
        pmax[cs * B_N + row] = mv;
        pidx[cs * B_N + row] = mi;
    }
}

// Finalize: merge CSPLIT partials per row, compute loss/accuracy means.
// Single block of 1024 threads; writes d_out directly (no memset needed).
__launch_bounds__(1024, 1)
__global__ void fin_kernel(const float* __restrict__ pden, const float* __restrict__ pnum,
                           const float* __restrict__ pmax, const int* __restrict__ pidx,
                           const int* __restrict__ qids, float* __restrict__ out) {
    float lsum = 0.f, csum = 0.f;
    for (int r = threadIdx.x; r < B_N; r += 1024) {
        float d = pden[r] + pden[B_N + r];
        float n = pnum[r] + pnum[B_N + r];
        float m0 = pmax[r], m1 = pmax[B_N + r];
        int   i0 = pidx[r], i1 = pidx[B_N + r];
        int   mi = (m1 > m0 || (m1 == m0 && i1 < i0)) ? i1 : i0;
        lsum += -logf(n / d + 1e-8f);
        csum += (qids[mi] == qids[r]) ? 1.0f : 0.0f;
    }
    #pragma unroll
    for (int m = 1; m <= 32; m <<= 1) {
        lsum += __shfl_xor(lsum, m, 64);
        csum += __shfl_xor(csum, m, 64);
    }
    __shared__ float sl[16], sc[16];
    const int wave = threadIdx.x >> 6;
    if ((threadIdx.x & 63) == 0) { sl[wave] = lsum; sc[wave] = csum; }
    __syncthreads();
    if (threadIdx.x == 0) {
        float L = 0.f, C = 0.f;
        #pragma unroll
        for (int w = 0; w < 16; ++w) { L += sl[w]; C += sc[w]; }
        out[0] = L * (1.0f / B_N);
        out[1] = C * (1.0f / B_N);
    }
}

extern "C" void kernel_launch(void* const* d_in, const int* in_sizes, int n_in,
                              void* d_out, int out_size, void* d_ws, size_t ws_size,
                              hipStream_t stream) {
    const float* q     = (const float*)d_in[0];
    const float* a     = (const float*)d_in[1];
    const int*   qids  = (const int*)d_in[2];
    const float* ranks = (const float*)d_in[3];
    float* out = (float*)d_out;

    unsigned short* qb = (unsigned short*)d_ws;
    unsigned short* ab = qb + (size_t)B_N * D_K;
    char* p = (char*)(ab + (size_t)B_N * D_K);
    float* pden = (float*)p;                 p += CSPLIT * B_N * sizeof(float);
    float* pnum = (float*)p;                 p += CSPLIT * B_N * sizeof(float);
    float* pmax = (float*)p;                 p += CSPLIT * B_N * sizeof(float);
    int*   pidx = (int*)p;

    cvt_kernel<<<(B_N * D_K / 4) / 256, 256, 0, stream>>>(q, a, qb, ab);
    mpl_part_kernel<<<256 * CSPLIT, 512, 0, stream>>>(qb, ab, qids, ranks, pden, pnum, pmax, pidx);
    fin_kernel<<<1, 1024, 0, stream>>>(pden, pnum, pmax, pidx, qids, out);
}

// Round 3
// 140.766 us; speedup vs baseline: 1.3813x; 1.3813x over previous
//
#include <hip/hip_runtime.h>
#include <hip/hip_bf16.h>
#include <cmath>

#define B_N 8192
#define D_K 128
#define CSPLIT 4           // column splits; block covers 2048 cols
#define T_ITERS 32         // 16-col tiles per wave: 2048/4 waves/16

typedef short bf16x8 __attribute__((ext_vector_type(8)));
typedef float f32x4  __attribute__((ext_vector_type(4)));

__device__ inline unsigned short f2bf(float f) {
    unsigned u = __builtin_bit_cast(unsigned, f);
    u += 0x7fffu + ((u >> 16) & 1u);   // round-to-nearest-even
    return (unsigned short)(u >> 16);
}

// Convert fp32 Q and A to bf16 in workspace. One thread per 4 elements.
__global__ void cvt_kernel(const float* __restrict__ q, const float* __restrict__ a,
                           unsigned short* __restrict__ qb, unsigned short* __restrict__ ab) {
    int i = blockIdx.x * blockDim.x + threadIdx.x;   // 0 .. B*D/4-1
    float4 vq = reinterpret_cast<const float4*>(q)[i];
    float4 va = reinterpret_cast<const float4*>(a)[i];
    ushort4 oq, oa;
    oq.x = f2bf(vq.x); oq.y = f2bf(vq.y); oq.z = f2bf(vq.z); oq.w = f2bf(vq.w);
    oa.x = f2bf(va.x); oa.y = f2bf(va.y); oa.z = f2bf(va.z); oa.w = f2bf(va.w);
    reinterpret_cast<ushort4*>(qb)[i] = oq;
    reinterpret_cast<ushort4*>(ab)[i] = oa;
}

// Partial kernel: block (rg, cs) computes rows [rg*32, rg*32+32) over cols
// [cs*2048, cs*2048+2048). 256 threads = 4 waves; wave w owns 512 cols.
// MFMA 16x16x32 bf16 (m89-verified layouts):
//   A-op: lane holds A[m=lane&15][k=(lane>>4)*8 + j], j=0..7
//   B-op: lane holds B[k=(lane>>4)*8 + j][n=lane&15]
//   C/D : col=lane&15, row=(lane>>4)*4 + reg
// Two 16-row tiles per wave (32 rows). Stats: den/num/mxv/mxp per (rt, reg).
// Accuracy via mxp (max over positive cols) == mxv (global max) — no argmax index.
// Register budget ~115 < 128 -> __launch_bounds__(256,4) = 16 waves/CU, NO spills
// (R2 lesson: WRITE_SIZE blowup = spills; keep live state lean).
__launch_bounds__(256, 4)
__global__ void mpl_part_kernel(const unsigned short* __restrict__ qb,
                                const unsigned short* __restrict__ ab,
                                const int* __restrict__ qids,
                                const float* __restrict__ ranks,
                                float* __restrict__ pden, float* __restrict__ pnum,
                                float* __restrict__ pmax, float* __restrict__ pmaxp) {
    const int tid  = threadIdx.x;
    const int lane = tid & 63;
    const int wave = tid >> 6;               // 0..3
    const int rg   = blockIdx.x >> 2;        // 0..255
    const int cs   = blockIdx.x & 3;         // 0..3  (XCD %8 -> one cs per XCD)
    const int rowBase = rg * 32;
    const int quad = lane >> 4;              // 0..3
    const int l15  = lane & 15;

    // Q fragments for K=128 (4 k-steps of 32) x 2 row-tiles, in registers (32 VGPRs).
    bf16x8 qfrag[2][4];
    #pragma unroll
    for (int rt = 0; rt < 2; ++rt) {
        const unsigned short* qrow = qb + (size_t)(rowBase + rt * 16 + l15) * D_K + quad * 8;
        #pragma unroll
        for (int s = 0; s < 4; ++s)
            qfrag[rt][s] = *reinterpret_cast<const bf16x8*>(qrow + s * 32);
    }

    int qidrow[2][4];
    #pragma unroll
    for (int rt = 0; rt < 2; ++rt)
        #pragma unroll
        for (int r = 0; r < 4; ++r)
            qidrow[rt][r] = qids[rowBase + rt * 16 + quad * 4 + r];

    float den[2][4], num[2][4], mxv[2][4], mxp[2][4];
    #pragma unroll
    for (int rt = 0; rt < 2; ++rt)
        #pragma unroll
        for (int r = 0; r < 4; ++r) {
            den[rt][r] = 0.f; num[rt][r] = 0.f;
            mxv[rt][r] = -INFINITY; mxp[rt][r] = -INFINITY;
        }

    const float L2E = 1.4426950408889634f;   // log2(e)
    const float CB  = 64.0f;                 // fixed exponent bias; cancels in num/den

    const int colStart = cs * 2048 + wave * 512;

    #pragma unroll 2
    for (int t = 0; t < T_ITERS; ++t) {
        const int c  = colStart + t * 16 + l15;
        const int qc = qids[c];
        const float wc = 1.0f - 0.1f * ranks[c];

        const unsigned short* arow = ab + (size_t)c * D_K + quad * 8;
        bf16x8 bfrag[4];
        #pragma unroll
        for (int s = 0; s < 4; ++s)
            bfrag[s] = *reinterpret_cast<const bf16x8*>(arow + s * 32);

        f32x4 acc0 = {0.f, 0.f, 0.f, 0.f};
        f32x4 acc1 = {0.f, 0.f, 0.f, 0.f};
        #pragma unroll
        for (int s = 0; s < 4; ++s) {
            acc0 = __builtin_amdgcn_mfma_f32_16x16x32_bf16(qfrag[0][s], bfrag[s], acc0, 0, 0, 0);
            acc1 = __builtin_amdgcn_mfma_f32_16x16x32_bf16(qfrag[1][s], bfrag[s], acc1, 0, 0, 0);
        }

        #pragma unroll
        for (int r = 0; r < 4; ++r) {
            {
                float sv = acc0[r];
                float e  = __builtin_amdgcn_exp2f(fmaf(sv, L2E, -CB));
                bool pos = (qc == qidrow[0][r]);
                den[0][r] += e;
                num[0][r] = fmaf(pos ? wc : 0.0f, e, num[0][r]);
                mxv[0][r] = fmaxf(mxv[0][r], sv);
                mxp[0][r] = fmaxf(mxp[0][r], pos ? sv : -INFINITY);
            }
            {
                float sv = acc1[r];
                float e  = __builtin_amdgcn_exp2f(fmaf(sv, L2E, -CB));
                bool pos = (qc == qidrow[1][r]);
                den[1][r] += e;
                num[1][r] = fmaf(pos ? wc : 0.0f, e, num[1][r]);
                mxv[1][r] = fmaxf(mxv[1][r], sv);
                mxp[1][r] = fmaxf(mxp[1][r], pos ? sv : -INFINITY);
            }
        }
    }

    // Reduce across the 16 lanes of each quad (same rows, different cols).
    #pragma unroll
    for (int m = 1; m <= 8; m <<= 1) {
        #pragma unroll
        for (int rt = 0; rt < 2; ++rt)
            #pragma unroll
            for (int r = 0; r < 4; ++r) {
                den[rt][r] += __shfl_xor(den[rt][r], m, 64);
                num[rt][r] += __shfl_xor(num[rt][r], m, 64);
                mxv[rt][r]  = fmaxf(mxv[rt][r], __shfl_xor(mxv[rt][r], m, 64));
                mxp[rt][r]  = fmaxf(mxp[rt][r], __shfl_xor(mxp[rt][r], m, 64));
            }
    }

    __shared__ float sden[4][32], snum[4][32], smax[4][32], smaxp[4][32];
    if (l15 == 0) {
        #pragma unroll
        for (int rt = 0; rt < 2; ++rt)
            #pragma unroll
            for (int r = 0; r < 4; ++r) {
                int lr = rt * 16 + quad * 4 + r;
                sden[wave][lr]  = den[rt][r];
                snum[wave][lr]  = num[rt][r];
                smax[wave][lr]  = mxv[rt][r];
                smaxp[wave][lr] = mxp[rt][r];
            }
    }
    __syncthreads();

    if (tid < 32) {
        int lr = tid;
        float d = 0.f, n = 0.f, mv = -INFINITY, mp = -INFINITY;
        #pragma unroll
        for (int w = 0; w < 4; ++w) {
            d += sden[w][lr];
            n += snum[w][lr];
            mv = fmaxf(mv, smax[w][lr]);
            mp = fmaxf(mp, smaxp[w][lr]);
        }
        const int row = rowBase + lr;
        pden[cs * B_N + row]  = d;
        pnum[cs * B_N + row]  = n;
        pmax[cs * B_N + row]  = mv;
        pmaxp[cs * B_N + row] = mp;
    }
}

// Finalize: merge CSPLIT partials per row, compute loss/accuracy means.
__launch_bounds__(1024, 1)
__global__ void fin_kernel(const float* __restrict__ pden, const float* __restrict__ pnum,
                           const float* __restrict__ pmax, const float* __restrict__ pmaxp,
                           float* __restrict__ out) {
    float lsum = 0.f, csum = 0.f;
    for (int r = threadIdx.x; r < B_N; r += 1024) {
        float d = 0.f, n = 0.f, mv = -INFINITY, mp = -INFINITY;
        #pragma unroll
        for (int cs = 0; cs < CSPLIT; ++cs) {
            d += pden[cs * B_N + r];
            n += pnum[cs * B_N + r];
            mv = fmaxf(mv, pmax[cs * B_N + r]);
            mp = fmaxf(mp, pmaxp[cs * B_N + r]);
        }
        lsum += -logf(n / d + 1e-8f);
        csum += (mp == mv) ? 1.0f : 0.0f;   // argmax col is positive <=> pos-max hits global max
    }
    #pragma unroll
    for (int m = 1; m <= 32; m <<= 1) {
        lsum += __shfl_xor(lsum, m, 64);
        csum += __shfl_xor(csum, m, 64);
    }
    __shared__ float sl[16], sc[16];
    const int wave = threadIdx.x >> 6;
    if ((threadIdx.x & 63) == 0) { sl[wave] = lsum; sc[wave] = csum; }
    __syncthreads();
    if (threadIdx.x == 0) {
        float L = 0.f, C = 0.f;
        #pragma unroll
        for (int w = 0; w < 16; ++w) { L += sl[w]; C += sc[w]; }
        out[0] = L * (1.0f / B_N);
        out[1] = C * (1.0f / B_N);
    }
}

extern "C" void kernel_launch(void* const* d_in, const int* in_sizes, int n_in,
                              void* d_out, int out_size, void* d_ws, size_t ws_size,
                              hipStream_t stream) {
    const float* q     = (const float*)d_in[0];
    const float* a     = (const float*)d_in[1];
    const int*   qids  = (const int*)d_in[2];
    const float* ranks = (const float*)d_in[3];
    float* out = (float*)d_out;

    unsigned short* qb = (unsigned short*)d_ws;
    unsigned short* ab = qb + (size_t)B_N * D_K;
    char* p = (char*)(ab + (size_t)B_N * D_K);
    float* pden  = (float*)p;                p += CSPLIT * B_N * sizeof(float);
    float* pnum  = (float*)p;                p += CSPLIT * B_N * sizeof(float);
    float* pmax  = (float*)p;                p += CSPLIT * B_N * sizeof(float);
    float* pmaxp = (float*)p;

    cvt_kernel<<<(B_N * D_K / 4) / 256, 256, 0, stream>>>(q, a, qb, ab);
    mpl_part_kernel<<<256 * CSPLIT, 256, 0, stream>>>(qb, ab, qids, ranks, pden, pnum, pmax, pmaxp);
    fin_kernel<<<1, 1024, 0, stream>>>(pden, pnum, pmax, pmaxp, out);
}

// Round 4
// 118.996 us; speedup vs baseline: 1.6340x; 1.1829x over previous
//
#include <hip/hip_runtime.h>
#include <hip/hip_bf16.h>
#include <cmath>

#define B_N 8192
#define D_K 128
#define CSPLIT 4           // column splits; block covers 2048 cols
#define T_ITERS 32         // 16-col tiles per wave: 2048/4 waves/16

typedef short bf16x8 __attribute__((ext_vector_type(8)));
typedef unsigned short u16x8 __attribute__((ext_vector_type(8)));
typedef float f32x4  __attribute__((ext_vector_type(4)));

__device__ inline unsigned short f2bf(float f) {
    unsigned u = __builtin_bit_cast(unsigned, f);
    u += 0x7fffu + ((u >> 16) & 1u);   // round-to-nearest-even
    return (unsigned short)(u >> 16);
}

// Convert fp32 Q (row-major bf16) and A (MFMA-fragment-packed bf16).
// A packed layout, bf16 element units: for col-tile T (16 cols), k-step s (32 k),
// chunk index = (T*4 + s)*64 + quad*16 + l15, each chunk = 8 bf16 (16 B) holding
// A[col = T*16 + l15][k = s*32 + quad*8 .. +7]. The main kernel's B-frag load is
// then base + lane*16B: 1 KB contiguous per wave instruction (4 lines/quarter-wave
// instead of 16 -> 4x fewer TA transactions; R3 diagnosis: TA-transaction-bound).
// One thread per 8 elements: g -> col = g>>4, sq = g&15 (s = sq>>2, quad = sq&3).
__global__ void cvt_kernel(const float* __restrict__ q, const float* __restrict__ a,
                           unsigned short* __restrict__ qb, unsigned short* __restrict__ ab) {
    int g = blockIdx.x * blockDim.x + threadIdx.x;   // 0 .. B*D/8-1
    // Q: row-major contiguous (coalesced load + store)
    float4 q0 = reinterpret_cast<const float4*>(q)[g * 2];
    float4 q1 = reinterpret_cast<const float4*>(q)[g * 2 + 1];
    u16x8 oq;
    oq[0] = f2bf(q0.x); oq[1] = f2bf(q0.y); oq[2] = f2bf(q0.z); oq[3] = f2bf(q0.w);
    oq[4] = f2bf(q1.x); oq[5] = f2bf(q1.y); oq[6] = f2bf(q1.z); oq[7] = f2bf(q1.w);
    *reinterpret_cast<u16x8*>(qb + (size_t)g * 8) = oq;

    // A: coalesced load (a + g*8 is contiguous since sq*8 = s*32+quad*8), packed store
    float4 a0 = reinterpret_cast<const float4*>(a)[g * 2];
    float4 a1 = reinterpret_cast<const float4*>(a)[g * 2 + 1];
    u16x8 oa;
    oa[0] = f2bf(a0.x); oa[1] = f2bf(a0.y); oa[2] = f2bf(a0.z); oa[3] = f2bf(a0.w);
    oa[4] = f2bf(a1.x); oa[5] = f2bf(a1.y); oa[6] = f2bf(a1.z); oa[7] = f2bf(a1.w);
    const int col = g >> 4, sq = g & 15, s = sq >> 2, quad = sq & 3;
    const int chunk = ((col >> 4) * 4 + s) * 64 + quad * 16 + (col & 15);
    *reinterpret_cast<u16x8*>(ab + (size_t)chunk * 8) = oa;
}

// Partial kernel: block (rg, cs) computes rows [rg*32, rg*32+32) over cols
// [cs*2048, cs*2048+2048). 256 threads = 4 waves; wave w owns 512 cols.
// MFMA 16x16x32 bf16 (m89-verified layouts):
//   A-op: lane holds A[m=lane&15][k=(lane>>4)*8 + j], j=0..7
//   B-op: lane holds B[k=(lane>>4)*8 + j][n=lane&15]
//   C/D : col=lane&15, row=(lane>>4)*4 + reg
// Accuracy via mxp (max over positive cols) == mxv (global max) — no argmax index.
__launch_bounds__(256, 4)
__global__ void mpl_part_kernel(const unsigned short* __restrict__ qb,
                                const unsigned short* __restrict__ ab,
                                const int* __restrict__ qids,
                                const float* __restrict__ ranks,
                                float* __restrict__ pden, float* __restrict__ pnum,
                                float* __restrict__ pmax, float* __restrict__ pmaxp) {
    const int tid  = threadIdx.x;
    const int lane = tid & 63;
    const int wave = tid >> 6;               // 0..3
    const int rg   = blockIdx.x >> 2;        // 0..255
    const int cs   = blockIdx.x & 3;         // 0..3  (XCD %8 -> one cs per XCD)
    const int rowBase = rg * 32;
    const int quad = lane >> 4;              // 0..3
    const int l15  = lane & 15;

    // Q fragments for K=128 (4 k-steps of 32) x 2 row-tiles, in registers (32 VGPRs).
    bf16x8 qfrag[2][4];
    #pragma unroll
    for (int rt = 0; rt < 2; ++rt) {
        const unsigned short* qrow = qb + (size_t)(rowBase + rt * 16 + l15) * D_K + quad * 8;
        #pragma unroll
        for (int s = 0; s < 4; ++s)
            qfrag[rt][s] = *reinterpret_cast<const bf16x8*>(qrow + s * 32);
    }

    int qidrow[2][4];
    #pragma unroll
    for (int rt = 0; rt < 2; ++rt)
        #pragma unroll
        for (int r = 0; r < 4; ++r)
            qidrow[rt][r] = qids[rowBase + rt * 16 + quad * 4 + r];

    float den[2][4], num[2][4], mxv[2][4], mxp[2][4];
    #pragma unroll
    for (int rt = 0; rt < 2; ++rt)
        #pragma unroll
        for (int r = 0; r < 4; ++r) {
            den[rt][r] = 0.f; num[rt][r] = 0.f;
            mxv[rt][r] = -INFINITY; mxp[rt][r] = -INFINITY;
        }

    const float L2E = 1.4426950408889634f;   // log2(e)
    const float CB  = 64.0f;                 // fixed exponent bias; cancels in num/den

    const int colStart = cs * 2048 + wave * 512;
    const int tileBase = colStart >> 4;      // first 16-col tile index for this wave

    #pragma unroll 2
    for (int t = 0; t < T_ITERS; ++t) {
        const int c  = colStart + t * 16 + l15;
        const int qc = qids[c];
        const float wc = 1.0f - 0.1f * ranks[c];

        // Packed B-frag: 1 KB contiguous per load instruction (lane*16B).
        const unsigned short* bbase = ab + ((size_t)(tileBase + t) * 4) * 512 + lane * 8;
        bf16x8 bfrag[4];
        #pragma unroll
        for (int s = 0; s < 4; ++s)
            bfrag[s] = *reinterpret_cast<const bf16x8*>(bbase + s * 512);

        f32x4 acc0 = {0.f, 0.f, 0.f, 0.f};
        f32x4 acc1 = {0.f, 0.f, 0.f, 0.f};
        #pragma unroll
        for (int s = 0; s < 4; ++s) {
            acc0 = __builtin_amdgcn_mfma_f32_16x16x32_bf16(qfrag[0][s], bfrag[s], acc0, 0, 0, 0);
            acc1 = __builtin_amdgcn_mfma_f32_16x16x32_bf16(qfrag[1][s], bfrag[s], acc1, 0, 0, 0);
        }

        #pragma unroll
        for (int r = 0; r < 4; ++r) {
            {
                float sv = acc0[r];
                float e  = __builtin_amdgcn_exp2f(fmaf(sv, L2E, -CB));
                bool pos = (qc == qidrow[0][r]);
                den[0][r] += e;
                num[0][r] = fmaf(pos ? wc : 0.0f, e, num[0][r]);
                mxv[0][r] = fmaxf(mxv[0][r], sv);
                mxp[0][r] = fmaxf(mxp[0][r], pos ? sv : -INFINITY);
            }
            {
                float sv = acc1[r];
                float e  = __builtin_amdgcn_exp2f(fmaf(sv, L2E, -CB));
                bool pos = (qc == qidrow[1][r]);
                den[1][r] += e;
                num[1][r] = fmaf(pos ? wc : 0.0f, e, num[1][r]);
                mxv[1][r] = fmaxf(mxv[1][r], sv);
                mxp[1][r] = fmaxf(mxp[1][r], pos ? sv : -INFINITY);
            }
        }
    }

    // Reduce across the 16 lanes of each quad (same rows, different cols).
    #pragma unroll
    for (int m = 1; m <= 8; m <<= 1) {
        #pragma unroll
        for (int rt = 0; rt < 2; ++rt)
            #pragma unroll
            for (int r = 0; r < 4; ++r) {
                den[rt][r] += __shfl_xor(den[rt][r], m, 64);
                num[rt][r] += __shfl_xor(num[rt][r], m, 64);
                mxv[rt][r]  = fmaxf(mxv[rt][r], __shfl_xor(mxv[rt][r], m, 64));
                mxp[rt][r]  = fmaxf(mxp[rt][r], __shfl_xor(mxp[rt][r], m, 64));
            }
    }

    __shared__ float sden[4][32], snum[4][32], smax[4][32], smaxp[4][32];
    if (l15 == 0) {
        #pragma unroll
        for (int rt = 0; rt < 2; ++rt)
            #pragma unroll
            for (int r = 0; r < 4; ++r) {
                int lr = rt * 16 + quad * 4 + r;
                sden[wave][lr]  = den[rt][r];
                snum[wave][lr]  = num[rt][r];
                smax[wave][lr]  = mxv[rt][r];
                smaxp[wave][lr] = mxp[rt][r];
            }
    }
    __syncthreads();

    if (tid < 32) {
        int lr = tid;
        float d = 0.f, n = 0.f, mv = -INFINITY, mp = -INFINITY;
        #pragma unroll
        for (int w = 0; w < 4; ++w) {
            d += sden[w][lr];
            n += snum[w][lr];
            mv = fmaxf(mv, smax[w][lr]);
            mp = fmaxf(mp, smaxp[w][lr]);
        }
        const int row = rowBase + lr;
        pden[cs * B_N + row]  = d;
        pnum[cs * B_N + row]  = n;
        pmax[cs * B_N + row]  = mv;
        pmaxp[cs * B_N + row] = mp;
    }
}

// Finalize: merge CSPLIT partials per row, compute loss/accuracy means.
__launch_bounds__(1024, 1)
__global__ void fin_kernel(const float* __restrict__ pden, const float* __restrict__ pnum,
                           const float* __restrict__ pmax, const float* __restrict__ pmaxp,
                           float* __restrict__ out) {
    float lsum = 0.f, csum = 0.f;
    for (int r = threadIdx.x; r < B_N; r += 1024) {
        float d = 0.f, n = 0.f, mv = -INFINITY, mp = -INFINITY;
        #pragma unroll
        for (int cs = 0; cs < CSPLIT; ++cs) {
            d += pden[cs * B_N + r];
            n += pnum[cs * B_N + r];
            mv = fmaxf(mv, pmax[cs * B_N + r]);
            mp = fmaxf(mp, pmaxp[cs * B_N + r]);
        }
        lsum += -logf(n / d + 1e-8f);
        csum += (mp == mv) ? 1.0f : 0.0f;   // argmax col is positive <=> pos-max hits global max
    }
    #pragma unroll
    for (int m = 1; m <= 32; m <<= 1) {
        lsum += __shfl_xor(lsum, m, 64);
        csum += __shfl_xor(csum, m, 64);
    }
    __shared__ float sl[16], sc[16];
    const int wave = threadIdx.x >> 6;
    if ((threadIdx.x & 63) == 0) { sl[wave] = lsum; sc[wave] = csum; }
    __syncthreads();
    if (threadIdx.x == 0) {
        float L = 0.f, C = 0.f;
        #pragma unroll
        for (int w = 0; w < 16; ++w) { L += sl[w]; C += sc[w]; }
        out[0] = L * (1.0f / B_N);
        out[1] = C * (1.0f / B_N);
    }
}

extern "C" void kernel_launch(void* const* d_in, const int* in_sizes, int n_in,
                              void* d_out, int out_size, void* d_ws, size_t ws_size,
                              hipStream_t stream) {
    const float* q     = (const float*)d_in[0];
    const float* a     = (const float*)d_in[1];
    const int*   qids  = (const int*)d_in[2];
    const float* ranks = (const float*)d_in[3];
    float* out = (float*)d_out;

    unsigned short* qb = (unsigned short*)d_ws;
    unsigned short* ab = qb + (size_t)B_N * D_K;
    char* p = (char*)(ab + (size_t)B_N * D_K);
    float* pden  = (float*)p;                p += CSPLIT * B_N * sizeof(float);
    float* pnum  = (float*)p;                p += CSPLIT * B_N * sizeof(float);
    float* pmax  = (float*)p;                p += CSPLIT * B_N * sizeof(float);
    float* pmaxp = (float*)p;

    cvt_kernel<<<(B_N * D_K / 8) / 256, 256, 0, stream>>>(q, a, qb, ab);
    mpl_part_kernel<<<256 * CSPLIT, 256, 0, stream>>>(qb, ab, qids, ranks, pden, pnum, pmax, pmaxp);
    fin_kernel<<<1, 1024, 0, stream>>>(pden, pnum, pmax, pmaxp, out);
}

// Round 5
// 115.014 us; speedup vs baseline: 1.6905x; 1.0346x over previous
//
#include <hip/hip_runtime.h>
#include <hip/hip_bf16.h>
#include <cmath>

#define B_N 8192
#define D_K 128
#define CSPLIT 8           // column splits; block covers 1024 cols; grid = 2048 = 8 blocks/CU
#define T_ITERS 16         // 16-col tiles per wave: 1024/4 waves/16

typedef short bf16x8 __attribute__((ext_vector_type(8)));
typedef unsigned short u16x8 __attribute__((ext_vector_type(8)));
typedef float f32x4  __attribute__((ext_vector_type(4)));

__device__ inline unsigned short f2bf(float f) {
    unsigned u = __builtin_bit_cast(unsigned, f);
    u += 0x7fffu + ((u >> 16) & 1u);   // round-to-nearest-even
    return (unsigned short)(u >> 16);
}

// Convert fp32 Q (row-major bf16) and A (MFMA-fragment-packed bf16).
// A packed layout, bf16 element units: for col-tile T (16 cols), k-step s (32 k),
// chunk index = (T*4 + s)*64 + quad*16 + l15, each chunk = 8 bf16 (16 B) holding
// A[col = T*16 + l15][k = s*32 + quad*8 .. +7]. Main kernel's B-frag load is then
// base + lane*16B: 1 KB contiguous per wave instruction (R4-verified win).
// Also zeroes d_out (harness re-poisons it to 0xAA before every replay).
__global__ void cvt_kernel(const float* __restrict__ q, const float* __restrict__ a,
                           unsigned short* __restrict__ qb, unsigned short* __restrict__ ab,
                           float* __restrict__ out) {
    int g = blockIdx.x * blockDim.x + threadIdx.x;   // 0 .. B*D/8-1
    if (g < 2) out[g] = 0.0f;
    // Q: row-major contiguous (coalesced load + store)
    float4 q0 = reinterpret_cast<const float4*>(q)[g * 2];
    float4 q1 = reinterpret_cast<const float4*>(q)[g * 2 + 1];
    u16x8 oq;
    oq[0] = f2bf(q0.x); oq[1] = f2bf(q0.y); oq[2] = f2bf(q0.z); oq[3] = f2bf(q0.w);
    oq[4] = f2bf(q1.x); oq[5] = f2bf(q1.y); oq[6] = f2bf(q1.z); oq[7] = f2bf(q1.w);
    *reinterpret_cast<u16x8*>(qb + (size_t)g * 8) = oq;

    // A: coalesced load, fragment-packed store
    float4 a0 = reinterpret_cast<const float4*>(a)[g * 2];
    float4 a1 = reinterpret_cast<const float4*>(a)[g * 2 + 1];
    u16x8 oa;
    oa[0] = f2bf(a0.x); oa[1] = f2bf(a0.y); oa[2] = f2bf(a0.z); oa[3] = f2bf(a0.w);
    oa[4] = f2bf(a1.x); oa[5] = f2bf(a1.y); oa[6] = f2bf(a1.z); oa[7] = f2bf(a1.w);
    const int col = g >> 4, sq = g & 15, s = sq >> 2, quad = sq & 3;
    const int chunk = ((col >> 4) * 4 + s) * 64 + quad * 16 + (col & 15);
    *reinterpret_cast<u16x8*>(ab + (size_t)chunk * 8) = oa;
}

// Partial kernel: block (rg, cs) computes rows [rg*32, rg*32+32) over cols
// [cs*1024, cs*1024+1024). 256 threads = 4 waves; wave w owns 256 cols.
// MFMA 16x16x32 bf16 (m89-verified layouts):
//   A-op: lane holds A[m=lane&15][k=(lane>>4)*8 + j], j=0..7
//   B-op: lane holds B[k=(lane>>4)*8 + j][n=lane&15]
//   C/D : col=lane&15, row=(lane>>4)*4 + reg
// Accuracy via mxp (max over positive cols) == mxv (global max) — no argmax index.
// VGPR=60, LDS=2KB -> 8 blocks/CU co-resident; grid 2048 = exactly one full round.
__launch_bounds__(256, 4)
__global__ void mpl_part_kernel(const unsigned short* __restrict__ qb,
                                const unsigned short* __restrict__ ab,
                                const int* __restrict__ qids,
                                const float* __restrict__ ranks,
                                float* __restrict__ pden, float* __restrict__ pnum,
                                float* __restrict__ pmax, float* __restrict__ pmaxp) {
    const int tid  = threadIdx.x;
    const int lane = tid & 63;
    const int wave = tid >> 6;               // 0..3
    const int rg   = blockIdx.x >> 3;        // 0..255
    const int cs   = blockIdx.x & 7;         // 0..7  (== XCD id under %8 dispatch)
    const int rowBase = rg * 32;
    const int quad = lane >> 4;              // 0..3
    const int l15  = lane & 15;

    // Q fragments for K=128 (4 k-steps of 32) x 2 row-tiles, in registers (32 VGPRs).
    bf16x8 qfrag[2][4];
    #pragma unroll
    for (int rt = 0; rt < 2; ++rt) {
        const unsigned short* qrow = qb + (size_t)(rowBase + rt * 16 + l15) * D_K + quad * 8;
        #pragma unroll
        for (int s = 0; s < 4; ++s)
            qfrag[rt][s] = *reinterpret_cast<const bf16x8*>(qrow + s * 32);
    }

    int qidrow[2][4];
    #pragma unroll
    for (int rt = 0; rt < 2; ++rt)
        #pragma unroll
        for (int r = 0; r < 4; ++r)
            qidrow[rt][r] = qids[rowBase + rt * 16 + quad * 4 + r];

    float den[2][4], num[2][4], mxv[2][4], mxp[2][4];
    #pragma unroll
    for (int rt = 0; rt < 2; ++rt)
        #pragma unroll
        for (int r = 0; r < 4; ++r) {
            den[rt][r] = 0.f; num[rt][r] = 0.f;
            mxv[rt][r] = -INFINITY; mxp[rt][r] = -INFINITY;
        }

    const float L2E = 1.4426950408889634f;   // log2(e)
    const float CB  = 64.0f;                 // fixed exponent bias; cancels in num/den

    const int colStart = cs * 1024 + wave * 256;
    const int tileBase = colStart >> 4;      // first 16-col tile index for this wave

    #pragma unroll 2
    for (int t = 0; t < T_ITERS; ++t) {
        const int c  = colStart + t * 16 + l15;
        const int qc = qids[c];
        const float wc = 1.0f - 0.1f * ranks[c];

        // Packed B-frag: 1 KB contiguous per load instruction (lane*16B).
        const unsigned short* bbase = ab + ((size_t)(tileBase + t) * 4) * 512 + lane * 8;
        bf16x8 bfrag[4];
        #pragma unroll
        for (int s = 0; s < 4; ++s)
            bfrag[s] = *reinterpret_cast<const bf16x8*>(bbase + s * 512);

        f32x4 acc0 = {0.f, 0.f, 0.f, 0.f};
        f32x4 acc1 = {0.f, 0.f, 0.f, 0.f};
        #pragma unroll
        for (int s = 0; s < 4; ++s) {
            acc0 = __builtin_amdgcn_mfma_f32_16x16x32_bf16(qfrag[0][s], bfrag[s], acc0, 0, 0, 0);
            acc1 = __builtin_amdgcn_mfma_f32_16x16x32_bf16(qfrag[1][s], bfrag[s], acc1, 0, 0, 0);
        }

        #pragma unroll
        for (int r = 0; r < 4; ++r) {
            {
                float sv = acc0[r];
                float e  = __builtin_amdgcn_exp2f(fmaf(sv, L2E, -CB));
                bool pos = (qc == qidrow[0][r]);
                den[0][r] += e;
                num[0][r] = fmaf(pos ? wc : 0.0f, e, num[0][r]);
                mxv[0][r] = fmaxf(mxv[0][r], sv);
                mxp[0][r] = fmaxf(mxp[0][r], pos ? sv : -INFINITY);
            }
            {
                float sv = acc1[r];
                float e  = __builtin_amdgcn_exp2f(fmaf(sv, L2E, -CB));
                bool pos = (qc == qidrow[1][r]);
                den[1][r] += e;
                num[1][r] = fmaf(pos ? wc : 0.0f, e, num[1][r]);
                mxv[1][r] = fmaxf(mxv[1][r], sv);
                mxp[1][r] = fmaxf(mxp[1][r], pos ? sv : -INFINITY);
            }
        }
    }

    // Reduce across the 16 lanes of each quad (same rows, different cols).
    #pragma unroll
    for (int m = 1; m <= 8; m <<= 1) {
        #pragma unroll
        for (int rt = 0; rt < 2; ++rt)
            #pragma unroll
            for (int r = 0; r < 4; ++r) {
                den[rt][r] += __shfl_xor(den[rt][r], m, 64);
                num[rt][r] += __shfl_xor(num[rt][r], m, 64);
                mxv[rt][r]  = fmaxf(mxv[rt][r], __shfl_xor(mxv[rt][r], m, 64));
                mxp[rt][r]  = fmaxf(mxp[rt][r], __shfl_xor(mxp[rt][r], m, 64));
            }
    }

    __shared__ float sden[4][32], snum[4][32], smax[4][32], smaxp[4][32];
    if (l15 == 0) {
        #pragma unroll
        for (int rt = 0; rt < 2; ++rt)
            #pragma unroll
            for (int r = 0; r < 4; ++r) {
                int lr = rt * 16 + quad * 4 + r;
                sden[wave][lr]  = den[rt][r];
                snum[wave][lr]  = num[rt][r];
                smax[wave][lr]  = mxv[rt][r];
                smaxp[wave][lr] = mxp[rt][r];
            }
    }
    __syncthreads();

    if (tid < 32) {
        int lr = tid;
        float d = 0.f, n = 0.f, mv = -INFINITY, mp = -INFINITY;
        #pragma unroll
        for (int w = 0; w < 4; ++w) {
            d += sden[w][lr];
            n += snum[w][lr];
            mv = fmaxf(mv, smax[w][lr]);
            mp = fmaxf(mp, smaxp[w][lr]);
        }
        const int row = rowBase + lr;
        pden[cs * B_N + row]  = d;
        pnum[cs * B_N + row]  = n;
        pmax[cs * B_N + row]  = mv;
        pmaxp[cs * B_N + row] = mp;
    }
}

// Finalize: 32 blocks x 256 threads, one row per thread (coalesced partial reads),
// block-reduce, atomicAdd into d_out (zeroed by cvt_kernel).
__launch_bounds__(256, 4)
__global__ void fin_kernel(const float* __restrict__ pden, const float* __restrict__ pnum,
                           const float* __restrict__ pmax, const float* __restrict__ pmaxp,
                           float* __restrict__ out) {
    const int r = blockIdx.x * 256 + threadIdx.x;
    float d = 0.f, n = 0.f, mv = -INFINITY, mp = -INFINITY;
    #pragma unroll
    for (int cs = 0; cs < CSPLIT; ++cs) {
        d += pden[cs * B_N + r];
        n += pnum[cs * B_N + r];
        mv = fmaxf(mv, pmax[cs * B_N + r]);
        mp = fmaxf(mp, pmaxp[cs * B_N + r]);
    }
    float lsum = -logf(n / d + 1e-8f);
    float csum = (mp == mv) ? 1.0f : 0.0f;   // argmax col positive <=> pos-max == global max
    #pragma unroll
    for (int m = 1; m <= 32; m <<= 1) {
        lsum += __shfl_xor(lsum, m, 64);
        csum += __shfl_xor(csum, m, 64);
    }
    __shared__ float sl[4], sc[4];
    const int wave = threadIdx.x >> 6;
    if ((threadIdx.x & 63) == 0) { sl[wave] = lsum; sc[wave] = csum; }
    __syncthreads();
    if (threadIdx.x == 0) {
        float L = sl[0] + sl[1] + sl[2] + sl[3];
        float C = sc[0] + sc[1] + sc[2] + sc[3];
        atomicAdd(&out[0], L * (1.0f / B_N));
        atomicAdd(&out[1], C * (1.0f / B_N));
    }
}

extern "C" void kernel_launch(void* const* d_in, const int* in_sizes, int n_in,
                              void* d_out, int out_size, void* d_ws, size_t ws_size,
                              hipStream_t stream) {
    const float* q     = (const float*)d_in[0];
    const float* a     = (const float*)d_in[1];
    const int*   qids  = (const int*)d_in[2];
    const float* ranks = (const float*)d_in[3];
    float* out = (float*)d_out;

    unsigned short* qb = (unsigned short*)d_ws;
    unsigned short* ab = qb + (size_t)B_N * D_K;
    char* p = (char*)(ab + (size_t)B_N * D_K);
    float* pden  = (float*)p;                p += CSPLIT * B_N * sizeof(float);
    float* pnum  = (float*)p;                p += CSPLIT * B_N * sizeof(float);
    float* pmax  = (float*)p;                p += CSPLIT * B_N * sizeof(float);
    float* pmaxp = (float*)p;

    cvt_kernel<<<(B_N * D_K / 8) / 256, 256, 0, stream>>>(q, a, qb, ab, out);
    mpl_part_kernel<<<256 * CSPLIT, 256, 0, stream>>>(qb, ab, qids, ranks, pden, pnum, pmax, pmaxp);
    fin_kernel<<<B_N / 256, 256, 0, stream>>>(pden, pnum, pmax, pmaxp, out);
}